// Round 2
// baseline (295.044 us; speedup 1.0000x reference)
//
#include <hip/hip_runtime.h>
#include <hip/hip_bf16.h>

#define B_    8
#define S_    32
#define H_    2048
#define NH_   16
#define NKV_  2
#define HD_   128
#define KV_   8192
#define G_    8
#define M_    256      /* B*S */
#define NQKV  2560     /* fused proj N: 2048 q | 256 k | 256 v */
#define NSP   16       /* kv splits */
#define SCALE_ 0.08838834764831845f

typedef __bf16 bf16x8 __attribute__((ext_vector_type(8)));
typedef float  f32x4  __attribute__((ext_vector_type(4)));
typedef float  f32x16 __attribute__((ext_vector_type(16)));

__device__ __forceinline__ unsigned short f2b(float f){
  unsigned u = __float_as_uint(f);
  u = u + 0x7FFFu + ((u>>16)&1u);           // RNE f32->bf16
  return (unsigned short)(u>>16);
}
__device__ __forceinline__ float b2f(unsigned short h){
  return __uint_as_float(((unsigned)h)<<16);
}
__device__ __forceinline__ unsigned pk2(float a, float b){
  return (unsigned)f2b(a) | ((unsigned)f2b(b)<<16);
}
__device__ __forceinline__ bf16x8 ld_frag(const unsigned short* p){
  union { uint4 u; bf16x8 b; } cv;
  cv.u = *(const uint4*)p;
  return cv.b;
}
__device__ __forceinline__ f32x4 mf(bf16x8 a, bf16x8 b, f32x4 c){
  return __builtin_amdgcn_mfma_f32_16x16x32_bf16(a, b, c, 0, 0, 0);
}
__device__ __forceinline__ f32x16 mf32(bf16x8 a, bf16x8 b, f32x16 c){
  return __builtin_amdgcn_mfma_f32_32x32x16_bf16(a, b, c, 0, 0, 0);
}
// swizzled LDS index (shorts); col multiple of 8 for 16B ops
__device__ __forceinline__ int swi(int row, int col){
  return row*128 + (col ^ ((((row)&15) ^ ((row>>1)&8)) << 3));
}

// ---------------- K0: hidden_states f32 -> bf16 ----------------
__global__ __launch_bounds__(256) void k_cvt(const float* __restrict__ x,
                                             unsigned short* __restrict__ y){
  const int i = (blockIdx.x*256 + threadIdx.x)*4;
  const float4 v = *(const float4*)(x + i);
  ushort4 o; o.x=f2b(v.x); o.y=f2b(v.y); o.z=f2b(v.z); o.w=f2b(v.w);
  *(ushort4*)(y + i) = o;
}

// ---------------- K1: fused QKV projection GEMM (bf16 MFMA) ----------------
__global__ __launch_bounds__(256) void k_gemm_qkv(
    const unsigned short* __restrict__ A,
    const float* __restrict__ qw, const float* __restrict__ kw, const float* __restrict__ vw,
    const float* __restrict__ qbv, const float* __restrict__ kbv, const float* __restrict__ vbv,
    float* __restrict__ out)
{
  __shared__ unsigned short As[64][56];
  __shared__ unsigned short Bs[64][56];
  const int n0 = blockIdx.x*64, m0 = blockIdx.y*64;
  const float* W; const float* bias; int ldw, wc0;
  if(n0 < 2048)      { W=qw; bias=qbv; ldw=2048; wc0=n0; }
  else if(n0 < 2304) { W=kw; bias=kbv; ldw=256;  wc0=n0-2048; }
  else               { W=vw; bias=vbv; ldw=256;  wc0=n0-2304; }
  const int t = threadIdx.x, lane = t&63, wid = t>>6;
  const int wr = wid>>1, wc = wid&1, l15 = lane&15, lq = lane>>4;
  const int ar = t>>2,  ac = (t&3)*8;
  const int bk = t>>5,  bn = (t&31)*2;
  f32x4 acc[2][2] = {};
  for(int k0 = 0; k0 < 2048; k0 += 32){
    __syncthreads();
    *(uint4*)(&As[ar][ac]) = *(const uint4*)(A + (m0+ar)*2048 + k0 + ac);
    #pragma unroll
    for(int p=0;p<4;p++){
      const int kk = bk + p*8;
      const float2 wv = *(const float2*)(W + (long)(k0+kk)*ldw + wc0 + bn);
      Bs[bn  ][kk] = f2b(wv.x);
      Bs[bn+1][kk] = f2b(wv.y);
    }
    __syncthreads();
    const bf16x8 a0 = ld_frag(&As[wr*32      + l15][lq*8]);
    const bf16x8 a1 = ld_frag(&As[wr*32 + 16 + l15][lq*8]);
    const bf16x8 b0 = ld_frag(&Bs[wc*32      + l15][lq*8]);
    const bf16x8 b1 = ld_frag(&Bs[wc*32 + 16 + l15][lq*8]);
    acc[0][0] = mf(a0,b0,acc[0][0]);
    acc[0][1] = mf(a0,b1,acc[0][1]);
    acc[1][0] = mf(a1,b0,acc[1][0]);
    acc[1][1] = mf(a1,b1,acc[1][1]);
  }
  #pragma unroll
  for(int mi=0;mi<2;mi++)
    #pragma unroll
    for(int nj=0;nj<2;nj++){
      const int col = n0 + wc*32 + nj*16 + l15;
      const float bv = bias[wc0 + wc*32 + nj*16 + l15];
      #pragma unroll
      for(int rr=0;rr<4;rr++){
        const int row = m0 + wr*32 + mi*16 + lq*4 + rr;
        out[row*NQKV + col] = acc[mi][nj][rr] + bv;
      }
    }
}

// ---------------- K2: RoPE + pack (Q bf16, new K/V f32) ----------------
__global__ __launch_bounds__(128) void k_rope(
    const float* __restrict__ raw, const float* __restrict__ cosb, const float* __restrict__ sinb,
    unsigned short* __restrict__ Qb, float* __restrict__ KnF, float* __restrict__ VnF)
{
  const int r = blockIdx.x, hh = blockIdx.y, d = threadIdx.x;
  const int b = r>>5, s = r&31;
  const float cv = cosb[(b*S_+s)*HD_ + d];
  const float sv = sinb[(b*S_+s)*HD_ + d];
  const int dp = (d<64)? d+64 : d-64;
  if(hh < 16){
    const float x  = raw[r*NQKV + hh*HD_ + d];
    const float xo = raw[r*NQKV + hh*HD_ + dp];
    const float y  = x*cv + ((d<64)? -xo : xo)*sv;
    const int kvh = hh>>3, g = hh&7;
    Qb[((long)(b*NKV_+kvh)*M_ + g*S_ + s)*HD_ + d] = f2b(y);
  } else if(hh < 18){
    const int kvh = hh-16;
    const float x  = raw[r*NQKV + 2048 + kvh*HD_ + d];
    const float xo = raw[r*NQKV + 2048 + kvh*HD_ + dp];
    KnF[((long)(b*NKV_+kvh)*S_ + s)*HD_ + d] = x*cv + ((d<64)? -xo : xo)*sv;
  } else {
    const int kvh = hh-18;
    VnF[((long)(b*NKV_+kvh)*S_ + s)*HD_ + d] = raw[r*NQKV + 2304 + kvh*HD_ + d];
  }
}

// ---------------- K3: split-KV attention, 32x32 MFMA, in-register softmax ----
// grid (sp=16, kv=2, b=8); 512 threads = 8 waves; each wave owns 32 q rows.
// Each block: 512 kv = 4 subtiles of 128, online softmax, double-buffered LDS.
__global__ __launch_bounds__(512, 2) void k_attn(
    const unsigned short* __restrict__ Qb,
    const float* __restrict__ KnF, const float* __restrict__ VnF,
    const float* __restrict__ kc, const float* __restrict__ vc,
    const float* __restrict__ mask, const int* __restrict__ rpp,
    unsigned short* __restrict__ num, float* __restrict__ mbuf, float* __restrict__ lbuf)
{
  __shared__ __align__(16) unsigned short lds[2][2][128*128]; // [buf][K|Vt]
  const int sp = blockIdx.x, kvh = blockIdx.y, b = blockIdx.z;
  const int bk = b*NKV_ + kvh;
  const int rp = *rpp;
  const int t = threadIdx.x, lane = t&63, wid = t>>6;
  const int l31 = lane&31, hi = lane>>5;
  const int kvbase = sp*512;
  // staging mappings
  const int krow = t>>2, khq = t&3;     // K: 128 rows x 4 col-quarters
  const int vhd  = t&127, vkq = t>>7;   // V: 128 hd rows x 4 kv-quarters

  // Q fragments, held in registers for whole block
  bf16x8 qf[8];
  { const unsigned short* qp = Qb + ((long)bk*M_ + wid*32 + l31)*HD_;
    #pragma unroll
    for(int ks=0;ks<8;ks++) qf[ks] = ld_frag(qp + ks*16 + hi*8); }

  float4 vK4[8];
  float  vV[32];

  auto loadK = [&](int tt){
    const int kvr = kvbase + tt*128 + krow;
    const float* kp = (kvr>=rp && kvr<rp+S_)
        ? (KnF + ((long)bk*S_ + (kvr-rp))*HD_ + khq*32)
        : (kc  + ((long)bk*KV_ + kvr)*HD_ + khq*32);
    #pragma unroll
    for(int i=0;i<8;i++) vK4[i] = *(const float4*)(kp + i*4);
  };
  auto loadV = [&](int tt){
    #pragma unroll
    for(int m=0;m<32;m++){
      const int kvr = kvbase + tt*128 + vkq*32 + m;   // wave-uniform
      const float* vp = (kvr>=rp && kvr<rp+S_)
          ? (VnF + ((long)bk*S_ + (kvr-rp))*HD_)
          : (vc  + ((long)bk*KV_ + kvr)*HD_);
      vV[m] = vp[vhd];
    }
  };
  auto writeK = [&](int bb){
    unsigned short* Sb = &lds[bb][0][0];
    #pragma unroll
    for(int i=0;i<4;i++){
      uint4 w4;
      w4.x = pk2(vK4[2*i].x,   vK4[2*i].y);
      w4.y = pk2(vK4[2*i].z,   vK4[2*i].w);
      w4.z = pk2(vK4[2*i+1].x, vK4[2*i+1].y);
      w4.w = pk2(vK4[2*i+1].z, vK4[2*i+1].w);
      *(uint4*)(Sb + swi(krow, khq*32 + i*8)) = w4;
    }
  };
  auto writeV = [&](int bb){
    unsigned short* Sb = &lds[bb][1][0];
    #pragma unroll
    for(int i=0;i<4;i++){
      uint4 w4;
      w4.x = pk2(vV[i*8+0], vV[i*8+1]);
      w4.y = pk2(vV[i*8+2], vV[i*8+3]);
      w4.z = pk2(vV[i*8+4], vV[i*8+5]);
      w4.w = pk2(vV[i*8+6], vV[i*8+7]);
      *(uint4*)(Sb + swi(vhd, vkq*32 + i*8)) = w4;
    }
  };

  // prologue: stage subtile 0 into buf 0
  loadK(0); loadV(0);
  writeK(0); writeV(0);
  __syncthreads();

  f32x16 oc[4] = {};
  float m_run = -3.0e38f, l_run = 0.f;

  for(int tt=0; tt<4; tt++){
    const int cur = tt&1;
    if(tt<3) loadK(tt+1);                       // K loads in flight across compute
    // ---- QK^T: sc[kvt] over kv = kvt*32 + (reg&3)+8*(reg>>2)+4*hi, q = l31 ----
    f32x16 sc[4] = {};
    { const unsigned short* Sk = &lds[cur][0][0];
      #pragma unroll
      for(int ks=0;ks<8;ks++){
        #pragma unroll
        for(int kvt=0;kvt<4;kvt++)
          sc[kvt] = mf32(ld_frag(Sk + swi(kvt*32 + l31, ks*16 + hi*8)), qf[ks], sc[kvt]);
      }
    }
    // ---- mask + scale + online max ----
    const float* mrow = mask + ((long)b*S_ + l31)*KV_ + kvbase + tt*128;
    float mx = m_run;
    #pragma unroll
    for(int kvt=0;kvt<4;kvt++){
      #pragma unroll
      for(int r4=0;r4<4;r4++){
        const float4 mk = *(const float4*)(mrow + kvt*32 + r4*8 + hi*4);
        sc[kvt][r4*4+0] = sc[kvt][r4*4+0]*SCALE_ + mk.x;
        sc[kvt][r4*4+1] = sc[kvt][r4*4+1]*SCALE_ + mk.y;
        sc[kvt][r4*4+2] = sc[kvt][r4*4+2]*SCALE_ + mk.z;
        sc[kvt][r4*4+3] = sc[kvt][r4*4+3]*SCALE_ + mk.w;
        mx = fmaxf(mx, fmaxf(fmaxf(sc[kvt][r4*4+0], sc[kvt][r4*4+1]),
                             fmaxf(sc[kvt][r4*4+2], sc[kvt][r4*4+3])));
      }
    }
    mx = fmaxf(mx, __shfl_xor(mx, 32, 64));
    const float scl = __expf(m_run - mx);       // first iter: exp(-huge)=0
    m_run = mx;
    // ---- exp + per-lane partial sum ----
    float psum = 0.f;
    #pragma unroll
    for(int kvt=0;kvt<4;kvt++)
      #pragma unroll
      for(int e=0;e<16;e++){
        const float p = __expf(sc[kvt][e] - mx);
        sc[kvt][e] = p; psum += p;
      }
    l_run = l_run*scl + psum;
    // ---- rescale O-acc (scale for q' fetched from lane q') ----
    #pragma unroll
    for(int r4=0;r4<4;r4++)
      #pragma unroll
      for(int rr=0;rr<4;rr++){
        const float sq = __shfl(scl, rr + 8*r4 + 4*hi, 64);
        #pragma unroll
        for(int ht=0;ht<4;ht++) oc[ht][r4*4+rr] *= sq;
      }
    // ---- pack P to bf16 pairs ----
    unsigned w_[4][4][2];
    #pragma unroll
    for(int kvt=0;kvt<4;kvt++)
      #pragma unroll
      for(int r4=0;r4<4;r4++){
        w_[kvt][r4][0] = pk2(sc[kvt][r4*4+0], sc[kvt][r4*4+1]);
        w_[kvt][r4][1] = pk2(sc[kvt][r4*4+2], sc[kvt][r4*4+3]);
      }
    if(tt<3) loadV(tt+1);                       // V loads in flight across PV
    // ---- PV: O[q][hd] += P x V ----
    { const unsigned short* Sv = &lds[cur][1][0];
      #pragma unroll
      for(int kvs=0;kvs<8;kvs++){
        const int kvt = kvs>>1, k2 = (kvs&1)*2;
        const unsigned wa0 = w_[kvt][k2  ][0], wa1 = w_[kvt][k2  ][1];
        const unsigned wb0 = w_[kvt][k2+1][0], wb1 = w_[kvt][k2+1][1];
        const unsigned own0 = hi? wb0:wa0, own1 = hi? wb1:wa1;
        const unsigned snd0 = hi? wa0:wb0, snd1 = hi? wa1:wb1;
        const unsigned rcv0 = __shfl_xor(snd0, 32, 64);
        const unsigned rcv1 = __shfl_xor(snd1, 32, 64);
        union{ unsigned u[4]; bf16x8 v; } ap;
        ap.u[0] = hi? rcv0:own0;  ap.u[1] = hi? rcv1:own1;
        ap.u[2] = hi? own0:rcv0;  ap.u[3] = hi? own1:rcv1;
        #pragma unroll
        for(int ht=0;ht<4;ht++)
          oc[ht] = mf32(ap.v, ld_frag(Sv + swi(ht*32 + l31, kvs*16 + hi*8)), oc[ht]);
      }
    }
    // ---- stage next subtile into other buffer ----
    if(tt<3){ writeK(cur^1); writeV(cur^1); }
    __syncthreads();
  }

  // ---- epilogue: write partials ----
  const float l_tot = l_run + __shfl_xor(l_run, 32, 64);
  if(lane < 32){
    const long base = ((long)bk*NSP + sp)*M_ + wid*32 + lane;
    mbuf[base] = m_run;
    lbuf[base] = l_tot;
  }
  unsigned short* np_ = num + (((long)bk*NSP + sp)*M_ + wid*32)*HD_;
  #pragma unroll
  for(int ht=0;ht<4;ht++)
    #pragma unroll
    for(int r4=0;r4<4;r4++)
      #pragma unroll
      for(int rr=0;rr<4;rr++){
        const int q = rr + 8*r4 + 4*hi;
        np_[(long)q*HD_ + ht*32 + l31] = f2b(oc[4*0+ht][r4*4+rr]);
      }
}

// ---------------- K4: combine split-KV partials ----------------
__global__ __launch_bounds__(128) void k_comb(
    const unsigned short* __restrict__ num, const float* __restrict__ mbuf,
    const float* __restrict__ lbuf, unsigned short* __restrict__ attnb)
{
  const int q = blockIdx.x, kvh = blockIdx.y, b = blockIdx.z, d = threadIdx.x;
  const int bk = b*NKV_ + kvh;
  float M = -3.0e38f;
  #pragma unroll
  for(int c=0;c<NSP;c++) M = fmaxf(M, mbuf[((long)bk*NSP + c)*M_ + q]);
  float den = 0.f, acc = 0.f;
  #pragma unroll
  for(int c=0;c<NSP;c++){
    const long ix = ((long)bk*NSP + c)*M_ + q;
    const float w = __expf(mbuf[ix] - M);
    den += lbuf[ix]*w;
    acc += w * b2f(num[ix*HD_ + d]);
  }
  const int g = q>>5, s = q&31, h = kvh*G_ + g;
  attnb[((long)(b*S_+s))*2048 + h*HD_ + d] = f2b(acc/den);
}

// ---------------- K5: output projection GEMM ----------------
__global__ __launch_bounds__(256) void k_gemm_o(
    const unsigned short* __restrict__ A,
    const float* __restrict__ W,
    float* __restrict__ out)
{
  __shared__ unsigned short As[64][56];
  __shared__ unsigned short Bs[64][56];
  const int n0 = blockIdx.x*64, m0 = blockIdx.y*64;
  const int t = threadIdx.x, lane = t&63, wid = t>>6;
  const int wr = wid>>1, wc = wid&1, l15 = lane&15, lq = lane>>4;
  const int ar = t>>2,  ac = (t&3)*8;
  const int bk = t>>5,  bn = (t&31)*2;
  f32x4 acc[2][2] = {};
  for(int k0 = 0; k0 < 2048; k0 += 32){
    __syncthreads();
    *(uint4*)(&As[ar][ac]) = *(const uint4*)(A + (m0+ar)*2048 + k0 + ac);
    #pragma unroll
    for(int p=0;p<4;p++){
      const int kk = bk + p*8;
      const float2 wv = *(const float2*)(W + (long)(k0+kk)*2048 + n0 + bn);
      Bs[bn  ][kk] = f2b(wv.x);
      Bs[bn+1][kk] = f2b(wv.y);
    }
    __syncthreads();
    const bf16x8 a0 = ld_frag(&As[wr*32      + l15][lq*8]);
    const bf16x8 a1 = ld_frag(&As[wr*32 + 16 + l15][lq*8]);
    const bf16x8 b0 = ld_frag(&Bs[wc*32      + l15][lq*8]);
    const bf16x8 b1 = ld_frag(&Bs[wc*32 + 16 + l15][lq*8]);
    acc[0][0] = mf(a0,b0,acc[0][0]);
    acc[0][1] = mf(a0,b1,acc[0][1]);
    acc[1][0] = mf(a1,b0,acc[1][0]);
    acc[1][1] = mf(a1,b1,acc[1][1]);
  }
  #pragma unroll
  for(int mi=0;mi<2;mi++)
    #pragma unroll
    for(int nj=0;nj<2;nj++){
      const int col = n0 + wc*32 + nj*16 + l15;
      #pragma unroll
      for(int rr=0;rr<4;rr++){
        const int row = m0 + wr*32 + mi*16 + lq*4 + rr;
        out[row*2048 + col] = acc[mi][nj][rr];
      }
    }
}

extern "C" void kernel_launch(void* const* d_in, const int* in_sizes, int n_in,
                              void* d_out, int out_size, void* d_ws, size_t ws_size,
                              hipStream_t stream){
  (void)in_sizes; (void)n_in; (void)out_size; (void)ws_size;
  const float* hs   = (const float*)d_in[0];
  const float* cosb = (const float*)d_in[1];
  const float* sinb = (const float*)d_in[2];
  const float* kc   = (const float*)d_in[3];
  const float* vc   = (const float*)d_in[4];
  const float* mask = (const float*)d_in[5];
  const int*   rp   = (const int*)  d_in[6];
  const float* qw   = (const float*)d_in[7];
  const float* qb   = (const float*)d_in[8];
  const float* kw   = (const float*)d_in[9];
  const float* kb   = (const float*)d_in[10];
  const float* vw   = (const float*)d_in[11];
  const float* vb   = (const float*)d_in[12];
  const float* ow   = (const float*)d_in[13];
  char* ws = (char*)d_ws;
  // ws layout (bytes)
  unsigned short* hsb   = (unsigned short*)(ws + 0);          // 1,048,576
  float*          raw   = (float*)         (ws + 1048576);    // 2,621,440
  unsigned short* Qb    = (unsigned short*)(ws + 3670016);    // 1,048,576
  float*          KnF   = (float*)         (ws + 4718592);    //   262,144
  float*          VnF   = (float*)         (ws + 4980736);    //   262,144
  unsigned short* attnb = (unsigned short*)(ws + 5242880);    // 1,048,576
  float*          mbuf  = (float*)         (ws + 6291456);    //   262,144
  float*          lbuf  = (float*)         (ws + 6553600);    //   262,144
  unsigned short* num   = (unsigned short*)(ws + 6815744);    // 16,777,216
  float* outp = (float*)d_out;

  k_cvt     <<<dim3(512),      dim3(256), 0, stream>>>(hs, hsb);
  k_gemm_qkv<<<dim3(40,4),     dim3(256), 0, stream>>>(hsb, qw,kw,vw, qb,kb,vb, raw);
  k_rope    <<<dim3(256,20),   dim3(128), 0, stream>>>(raw, cosb, sinb, Qb, KnF, VnF);
  k_attn    <<<dim3(NSP,2,8),  dim3(512), 0, stream>>>(Qb, KnF, VnF, kc, vc, mask, rp, num, mbuf, lbuf);
  k_comb    <<<dim3(256,2,8),  dim3(128), 0, stream>>>(num, mbuf, lbuf, attnb);
  k_gemm_o  <<<dim3(32,4),     dim3(256), 0, stream>>>(attnb, ow, outp);
}

// Round 3
// 182.630 us; speedup vs baseline: 1.6155x; 1.6155x over previous
//
#include <hip/hip_runtime.h>
#include <hip/hip_bf16.h>

#define B_    8
#define S_    32
#define H_    2048
#define NH_   16
#define NKV_  2
#define HD_   128
#define KV_   8192
#define G_    8
#define M_    256      /* B*S */
#define NQKV  2560     /* fused proj N: 2048 q | 256 k | 256 v */
#define NSP   16       /* kv splits */
#define KT_   64       /* kv subtile */
#define SCALE_ 0.08838834764831845f

typedef __bf16 bf16x8 __attribute__((ext_vector_type(8)));
typedef float  f32x4  __attribute__((ext_vector_type(4)));
typedef float  f32x16 __attribute__((ext_vector_type(16)));

__device__ __forceinline__ unsigned short f2b(float f){
  unsigned u = __float_as_uint(f);
  u = u + 0x7FFFu + ((u>>16)&1u);           // RNE f32->bf16
  return (unsigned short)(u>>16);
}
__device__ __forceinline__ float b2f(unsigned short h){
  return __uint_as_float(((unsigned)h)<<16);
}
__device__ __forceinline__ unsigned pk2(float a, float b){
  return (unsigned)f2b(a) | ((unsigned)f2b(b)<<16);
}
__device__ __forceinline__ bf16x8 ld_frag(const unsigned short* p){
  union { uint4 u; bf16x8 b; } cv;
  cv.u = *(const uint4*)p;
  return cv.b;
}
__device__ __forceinline__ f32x4 mf(bf16x8 a, bf16x8 b, f32x4 c){
  return __builtin_amdgcn_mfma_f32_16x16x32_bf16(a, b, c, 0, 0, 0);
}
__device__ __forceinline__ f32x16 mf32(bf16x8 a, bf16x8 b, f32x16 c){
  return __builtin_amdgcn_mfma_f32_32x32x16_bf16(a, b, c, 0, 0, 0);
}
// K tile swizzle: 64 rows x 128 cols (shorts), 16B-group XOR
__device__ __forceinline__ int swiK(int row, int col){
  return row*128 + (col ^ ((((row)&15) ^ ((row>>1)&8)) << 3));
}
// Vt tile swizzle: 128 rows x 64 cols (shorts)
__device__ __forceinline__ int swiV(int row, int col){
  return row*64 + (col ^ (((row)&7) << 3));
}

// ---------------- K0: hidden_states f32 -> bf16 ----------------
__global__ __launch_bounds__(256) void k_cvt(const float* __restrict__ x,
                                             unsigned short* __restrict__ y){
  const int i = (blockIdx.x*256 + threadIdx.x)*4;
  const float4 v = *(const float4*)(x + i);
  ushort4 o; o.x=f2b(v.x); o.y=f2b(v.y); o.z=f2b(v.z); o.w=f2b(v.w);
  *(ushort4*)(y + i) = o;
}

// ---------------- K1: fused QKV projection GEMM (bf16 MFMA) ----------------
__global__ __launch_bounds__(256) void k_gemm_qkv(
    const unsigned short* __restrict__ A,
    const float* __restrict__ qw, const float* __restrict__ kw, const float* __restrict__ vw,
    const float* __restrict__ qbv, const float* __restrict__ kbv, const float* __restrict__ vbv,
    float* __restrict__ out)
{
  __shared__ unsigned short As[64][56];
  __shared__ unsigned short Bs[64][56];
  const int n0 = blockIdx.x*64, m0 = blockIdx.y*64;
  const float* W; const float* bias; int ldw, wc0;
  if(n0 < 2048)      { W=qw; bias=qbv; ldw=2048; wc0=n0; }
  else if(n0 < 2304) { W=kw; bias=kbv; ldw=256;  wc0=n0-2048; }
  else               { W=vw; bias=vbv; ldw=256;  wc0=n0-2304; }
  const int t = threadIdx.x, lane = t&63, wid = t>>6;
  const int wr = wid>>1, wc = wid&1, l15 = lane&15, lq = lane>>4;
  const int ar = t>>2,  ac = (t&3)*8;
  const int bk = t>>5,  bn = (t&31)*2;
  f32x4 acc[2][2] = {};
  for(int k0 = 0; k0 < 2048; k0 += 32){
    __syncthreads();
    *(uint4*)(&As[ar][ac]) = *(const uint4*)(A + (m0+ar)*2048 + k0 + ac);
    #pragma unroll
    for(int p=0;p<4;p++){
      const int kk = bk + p*8;
      const float2 wv = *(const float2*)(W + (long)(k0+kk)*ldw + wc0 + bn);
      Bs[bn  ][kk] = f2b(wv.x);
      Bs[bn+1][kk] = f2b(wv.y);
    }
    __syncthreads();
    const bf16x8 a0 = ld_frag(&As[wr*32      + l15][lq*8]);
    const bf16x8 a1 = ld_frag(&As[wr*32 + 16 + l15][lq*8]);
    const bf16x8 b0 = ld_frag(&Bs[wc*32      + l15][lq*8]);
    const bf16x8 b1 = ld_frag(&Bs[wc*32 + 16 + l15][lq*8]);
    acc[0][0] = mf(a0,b0,acc[0][0]);
    acc[0][1] = mf(a0,b1,acc[0][1]);
    acc[1][0] = mf(a1,b0,acc[1][0]);
    acc[1][1] = mf(a1,b1,acc[1][1]);
  }
  #pragma unroll
  for(int mi=0;mi<2;mi++)
    #pragma unroll
    for(int nj=0;nj<2;nj++){
      const int col = n0 + wc*32 + nj*16 + l15;
      const float bv = bias[wc0 + wc*32 + nj*16 + l15];
      #pragma unroll
      for(int rr=0;rr<4;rr++){
        const int row = m0 + wr*32 + mi*16 + lq*4 + rr;
        out[row*NQKV + col] = acc[mi][nj][rr] + bv;
      }
    }
}

// ---------------- K2: RoPE + pack (Q bf16, new K/V f32) ----------------
__global__ __launch_bounds__(128) void k_rope(
    const float* __restrict__ raw, const float* __restrict__ cosb, const float* __restrict__ sinb,
    unsigned short* __restrict__ Qb, float* __restrict__ KnF, float* __restrict__ VnF)
{
  const int r = blockIdx.x, hh = blockIdx.y, d = threadIdx.x;
  const int b = r>>5, s = r&31;
  const float cv = cosb[(b*S_+s)*HD_ + d];
  const float sv = sinb[(b*S_+s)*HD_ + d];
  const int dp = (d<64)? d+64 : d-64;
  if(hh < 16){
    const float x  = raw[r*NQKV + hh*HD_ + d];
    const float xo = raw[r*NQKV + hh*HD_ + dp];
    const float y  = x*cv + ((d<64)? -xo : xo)*sv;
    const int kvh = hh>>3, g = hh&7;
    Qb[((long)(b*NKV_+kvh)*M_ + g*S_ + s)*HD_ + d] = f2b(y);
  } else if(hh < 18){
    const int kvh = hh-16;
    const float x  = raw[r*NQKV + 2048 + kvh*HD_ + d];
    const float xo = raw[r*NQKV + 2048 + kvh*HD_ + dp];
    KnF[((long)(b*NKV_+kvh)*S_ + s)*HD_ + d] = x*cv + ((d<64)? -xo : xo)*sv;
  } else {
    const int kvh = hh-18;
    VnF[((long)(b*NKV_+kvh)*S_ + s)*HD_ + d] = raw[r*NQKV + 2304 + kvh*HD_ + d];
  }
}

// ---------------- K3: split-KV attention, 32x32 MFMA, in-register softmax ----
// grid (sp=16, kv=2, b=8); 512 threads = 8 waves; each wave owns 32 q rows.
// Each block: 512 kv = 8 subtiles of KT_=64, online softmax, double-buffered LDS.
__global__ __launch_bounds__(512) void k_attn(
    const unsigned short* __restrict__ Qb,
    const float* __restrict__ KnF, const float* __restrict__ VnF,
    const float* __restrict__ kc, const float* __restrict__ vc,
    const float* __restrict__ mask, const int* __restrict__ rpp,
    unsigned short* __restrict__ num, float* __restrict__ mbuf, float* __restrict__ lbuf)
{
  __shared__ __align__(16) unsigned short lds[2][2][KT_*128]; // [buf][K|Vt] 64KB
  const int sp = blockIdx.x, kvh = blockIdx.y, b = blockIdx.z;
  const int bk = b*NKV_ + kvh;
  const int rp = *rpp;
  const int t = threadIdx.x, lane = t&63, wid = t>>6;
  const int l31 = lane&31, hi = lane>>5;
  const int kvbase = sp*512;
  // staging mappings
  const int krow = t>>3, kc0 = (t&7)*16;  // K: 64 rows x 8 col-eighths (16 f32 each)
  const int vhd  = t&127, vkq = t>>7;     // V: 128 hd cols x 4 kv-quarters (16 rows each)

  // Q fragments, held in registers for whole block
  bf16x8 qf[8];
  { const unsigned short* qp = Qb + ((long)bk*M_ + wid*32 + l31)*HD_;
    #pragma unroll
    for(int ks=0;ks<8;ks++) qf[ks] = ld_frag(qp + ks*16 + hi*8); }

  float4 vK4[4];
  float  vV[16];

  auto loadK = [&](int tt){
    const int kvr = kvbase + tt*KT_ + krow;
    const float* kp = (kvr>=rp && kvr<rp+S_)
        ? (KnF + ((long)bk*S_ + (kvr-rp))*HD_ + kc0)
        : (kc  + ((long)bk*KV_ + kvr)*HD_ + kc0);
    #pragma unroll
    for(int i=0;i<4;i++) vK4[i] = *(const float4*)(kp + i*4);
  };
  auto loadV = [&](int tt){
    #pragma unroll
    for(int m=0;m<16;m++){
      const int kvr = kvbase + tt*KT_ + vkq*16 + m;   // wave-uniform row
      const float* vp = (kvr>=rp && kvr<rp+S_)
          ? (VnF + ((long)bk*S_ + (kvr-rp))*HD_)
          : (vc  + ((long)bk*KV_ + kvr)*HD_);
      vV[m] = vp[vhd];
    }
  };
  auto writeK = [&](int bb){
    unsigned short* Sb = &lds[bb][0][0];
    uint4 w4;
    w4.x = pk2(vK4[0].x, vK4[0].y);  w4.y = pk2(vK4[0].z, vK4[0].w);
    w4.z = pk2(vK4[1].x, vK4[1].y);  w4.w = pk2(vK4[1].z, vK4[1].w);
    *(uint4*)(Sb + swiK(krow, kc0)) = w4;
    w4.x = pk2(vK4[2].x, vK4[2].y);  w4.y = pk2(vK4[2].z, vK4[2].w);
    w4.z = pk2(vK4[3].x, vK4[3].y);  w4.w = pk2(vK4[3].z, vK4[3].w);
    *(uint4*)(Sb + swiK(krow, kc0 + 8)) = w4;
  };
  auto writeV = [&](int bb){
    unsigned short* Sb = &lds[bb][1][0];
    uint4 w4;
    w4.x = pk2(vV[0], vV[1]);   w4.y = pk2(vV[2], vV[3]);
    w4.z = pk2(vV[4], vV[5]);   w4.w = pk2(vV[6], vV[7]);
    *(uint4*)(Sb + swiV(vhd, vkq*16)) = w4;
    w4.x = pk2(vV[8], vV[9]);   w4.y = pk2(vV[10], vV[11]);
    w4.z = pk2(vV[12], vV[13]); w4.w = pk2(vV[14], vV[15]);
    *(uint4*)(Sb + swiV(vhd, vkq*16 + 8)) = w4;
  };

  // prologue: stage subtile 0 into buf 0
  loadK(0); loadV(0);
  writeK(0); writeV(0);
  __syncthreads();

  f32x16 oc[4] = {};
  float m_run = -3.0e38f, l_run = 0.f;

  for(int tt=0; tt<8; tt++){
    const int cur = tt&1;
    if(tt<7) loadK(tt+1);                      // K loads in flight across compute
    // ---- QK^T: sc[kvt], kv = kvt*32 + (e&3)+8*(e>>2)+4*hi, q = l31 ----
    f32x16 sc[2] = {};
    { const unsigned short* Sk = &lds[cur][0][0];
      __builtin_amdgcn_s_setprio(1);
      #pragma unroll
      for(int ks=0;ks<8;ks++){
        #pragma unroll
        for(int kvt=0;kvt<2;kvt++)
          sc[kvt] = mf32(ld_frag(Sk + swiK(kvt*32 + l31, ks*16 + hi*8)), qf[ks], sc[kvt]);
      }
      __builtin_amdgcn_s_setprio(0);
    }
    if(tt<7) loadV(tt+1);                      // V loads in flight across softmax+PV
    // ---- mask + scale + online max ----
    const float* mrow = mask + ((long)b*S_ + l31)*KV_ + kvbase + tt*KT_;
    float mx = m_run;
    #pragma unroll
    for(int kvt=0;kvt<2;kvt++){
      #pragma unroll
      for(int r4=0;r4<4;r4++){
        const float4 mk = *(const float4*)(mrow + kvt*32 + r4*8 + hi*4);
        sc[kvt][r4*4+0] = sc[kvt][r4*4+0]*SCALE_ + mk.x;
        sc[kvt][r4*4+1] = sc[kvt][r4*4+1]*SCALE_ + mk.y;
        sc[kvt][r4*4+2] = sc[kvt][r4*4+2]*SCALE_ + mk.z;
        sc[kvt][r4*4+3] = sc[kvt][r4*4+3]*SCALE_ + mk.w;
        mx = fmaxf(mx, fmaxf(fmaxf(sc[kvt][r4*4+0], sc[kvt][r4*4+1]),
                             fmaxf(sc[kvt][r4*4+2], sc[kvt][r4*4+3])));
      }
    }
    mx = fmaxf(mx, __shfl_xor(mx, 32, 64));
    const float scl = __expf(m_run - mx);       // first iter: exp(-huge)=0
    m_run = mx;
    // ---- exp + per-lane partial sum ----
    float psum = 0.f;
    #pragma unroll
    for(int kvt=0;kvt<2;kvt++)
      #pragma unroll
      for(int e=0;e<16;e++){
        const float p = __expf(sc[kvt][e] - mx);
        sc[kvt][e] = p; psum += p;
      }
    l_run = l_run*scl + psum;
    // ---- rescale O-acc (scale for q' fetched from lane q') ----
    #pragma unroll
    for(int r4=0;r4<4;r4++)
      #pragma unroll
      for(int rr=0;rr<4;rr++){
        const float sq = __shfl(scl, rr + 8*r4 + 4*hi, 64);
        #pragma unroll
        for(int ht=0;ht<4;ht++) oc[ht][r4*4+rr] *= sq;
      }
    // ---- pack P to bf16 pairs ----
    unsigned w_[2][4][2];
    #pragma unroll
    for(int kvt=0;kvt<2;kvt++)
      #pragma unroll
      for(int r4=0;r4<4;r4++){
        w_[kvt][r4][0] = pk2(sc[kvt][r4*4+0], sc[kvt][r4*4+1]);
        w_[kvt][r4][1] = pk2(sc[kvt][r4*4+2], sc[kvt][r4*4+3]);
      }
    // ---- PV: O[q][hd] += P x V ----
    { const unsigned short* Sv = &lds[cur][1][0];
      __builtin_amdgcn_s_setprio(1);
      #pragma unroll
      for(int kvs=0;kvs<4;kvs++){
        const int kvt = kvs>>1, k2 = (kvs&1)*2;
        const unsigned wa0 = w_[kvt][k2  ][0], wa1 = w_[kvt][k2  ][1];
        const unsigned wb0 = w_[kvt][k2+1][0], wb1 = w_[kvt][k2+1][1];
        const unsigned own0 = hi? wb0:wa0, own1 = hi? wb1:wa1;
        const unsigned snd0 = hi? wa0:wb0, snd1 = hi? wa1:wb1;
        const unsigned rcv0 = __shfl_xor(snd0, 32, 64);
        const unsigned rcv1 = __shfl_xor(snd1, 32, 64);
        union{ unsigned u[4]; bf16x8 v; } ap;
        ap.u[0] = hi? rcv0:own0;  ap.u[1] = hi? rcv1:own1;
        ap.u[2] = hi? own0:rcv0;  ap.u[3] = hi? own1:rcv1;
        #pragma unroll
        for(int ht=0;ht<4;ht++)
          oc[ht] = mf32(ap.v, ld_frag(Sv + swiV(ht*32 + l31, kvs*16 + hi*8)), oc[ht]);
      }
      __builtin_amdgcn_s_setprio(0);
    }
    // ---- stage next subtile into other buffer ----
    if(tt<7){ writeK(cur^1); writeV(cur^1); }
    __syncthreads();
  }

  // ---- epilogue: write partials ----
  const float l_tot = l_run + __shfl_xor(l_run, 32, 64);
  if(lane < 32){
    const long base = ((long)bk*NSP + sp)*M_ + wid*32 + lane;
    mbuf[base] = m_run;
    lbuf[base] = l_tot;
  }
  unsigned short* np_ = num + (((long)bk*NSP + sp)*M_ + wid*32)*HD_;
  #pragma unroll
  for(int ht=0;ht<4;ht++)
    #pragma unroll
    for(int r4=0;r4<4;r4++)
      #pragma unroll
      for(int rr=0;rr<4;rr++){
        const int q = rr + 8*r4 + 4*hi;
        np_[(long)q*HD_ + ht*32 + l31] = f2b(oc[ht][r4*4+rr]);
      }
}

// ---------------- K4: combine split-KV partials ----------------
__global__ __launch_bounds__(128) void k_comb(
    const unsigned short* __restrict__ num, const float* __restrict__ mbuf,
    const float* __restrict__ lbuf, unsigned short* __restrict__ attnb)
{
  const int q = blockIdx.x, kvh = blockIdx.y, b = blockIdx.z, d = threadIdx.x;
  const int bk = b*NKV_ + kvh;
  float M = -3.0e38f;
  #pragma unroll
  for(int c=0;c<NSP;c++) M = fmaxf(M, mbuf[((long)bk*NSP + c)*M_ + q]);
  float den = 0.f, acc = 0.f;
  #pragma unroll
  for(int c=0;c<NSP;c++){
    const long ix = ((long)bk*NSP + c)*M_ + q;
    const float w = __expf(mbuf[ix] - M);
    den += lbuf[ix]*w;
    acc += w * b2f(num[ix*HD_ + d]);
  }
  const int g = q>>5, s = q&31, h = kvh*G_ + g;
  attnb[((long)(b*S_+s))*2048 + h*HD_ + d] = f2b(acc/den);
}

// ---------------- K5: output projection GEMM ----------------
__global__ __launch_bounds__(256) void k_gemm_o(
    const unsigned short* __restrict__ A,
    const float* __restrict__ W,
    float* __restrict__ out)
{
  __shared__ unsigned short As[64][56];
  __shared__ unsigned short Bs[64][56];
  const int n0 = blockIdx.x*64, m0 = blockIdx.y*64;
  const int t = threadIdx.x, lane = t&63, wid = t>>6;
  const int wr = wid>>1, wc = wid&1, l15 = lane&15, lq = lane>>4;
  const int ar = t>>2,  ac = (t&3)*8;
  const int bk = t>>5,  bn = (t&31)*2;
  f32x4 acc[2][2] = {};
  for(int k0 = 0; k0 < 2048; k0 += 32){
    __syncthreads();
    *(uint4*)(&As[ar][ac]) = *(const uint4*)(A + (m0+ar)*2048 + k0 + ac);
    #pragma unroll
    for(int p=0;p<4;p++){
      const int kk = bk + p*8;
      const float2 wv = *(const float2*)(W + (long)(k0+kk)*2048 + n0 + bn);
      Bs[bn  ][kk] = f2b(wv.x);
      Bs[bn+1][kk] = f2b(wv.y);
    }
    __syncthreads();
    const bf16x8 a0 = ld_frag(&As[wr*32      + l15][lq*8]);
    const bf16x8 a1 = ld_frag(&As[wr*32 + 16 + l15][lq*8]);
    const bf16x8 b0 = ld_frag(&Bs[wc*32      + l15][lq*8]);
    const bf16x8 b1 = ld_frag(&Bs[wc*32 + 16 + l15][lq*8]);
    acc[0][0] = mf(a0,b0,acc[0][0]);
    acc[0][1] = mf(a0,b1,acc[0][1]);
    acc[1][0] = mf(a1,b0,acc[1][0]);
    acc[1][1] = mf(a1,b1,acc[1][1]);
  }
  #pragma unroll
  for(int mi=0;mi<2;mi++)
    #pragma unroll
    for(int nj=0;nj<2;nj++){
      const int col = n0 + wc*32 + nj*16 + l15;
      #pragma unroll
      for(int rr=0;rr<4;rr++){
        const int row = m0 + wr*32 + mi*16 + lq*4 + rr;
        out[row*2048 + col] = acc[mi][nj][rr];
      }
    }
}

extern "C" void kernel_launch(void* const* d_in, const int* in_sizes, int n_in,
                              void* d_out, int out_size, void* d_ws, size_t ws_size,
                              hipStream_t stream){
  (void)in_sizes; (void)n_in; (void)out_size; (void)ws_size;
  const float* hs   = (const float*)d_in[0];
  const float* cosb = (const float*)d_in[1];
  const float* sinb = (const float*)d_in[2];
  const float* kc   = (const float*)d_in[3];
  const float* vc   = (const float*)d_in[4];
  const float* mask = (const float*)d_in[5];
  const int*   rp   = (const int*)  d_in[6];
  const float* qw   = (const float*)d_in[7];
  const float* qb   = (const float*)d_in[8];
  const float* kw   = (const float*)d_in[9];
  const float* kb   = (const float*)d_in[10];
  const float* vw   = (const float*)d_in[11];
  const float* vb   = (const float*)d_in[12];
  const float* ow   = (const float*)d_in[13];
  char* ws = (char*)d_ws;
  // ws layout (bytes)
  unsigned short* hsb   = (unsigned short*)(ws + 0);          // 1,048,576
  float*          raw   = (float*)         (ws + 1048576);    // 2,621,440
  unsigned short* Qb    = (unsigned short*)(ws + 3670016);    // 1,048,576
  float*          KnF   = (float*)         (ws + 4718592);    //   262,144
  float*          VnF   = (float*)         (ws + 4980736);    //   262,144
  unsigned short* attnb = (unsigned short*)(ws + 5242880);    // 1,048,576
  float*          mbuf  = (float*)         (ws + 6291456);    //   262,144
  float*          lbuf  = (float*)         (ws + 6553600);    //   262,144
  unsigned short* num   = (unsigned short*)(ws + 6815744);    // 16,777,216
  float* outp = (float*)d_out;

  k_cvt     <<<dim3(512),      dim3(256), 0, stream>>>(hs, hsb);
  k_gemm_qkv<<<dim3(40,4),     dim3(256), 0, stream>>>(hsb, qw,kw,vw, qb,kb,vb, raw);
  k_rope    <<<dim3(256,20),   dim3(128), 0, stream>>>(raw, cosb, sinb, Qb, KnF, VnF);
  k_attn    <<<dim3(NSP,2,8),  dim3(512), 0, stream>>>(Qb, KnF, VnF, kc, vc, mask, rp, num, mbuf, lbuf);
  k_comb    <<<dim3(256,2,8),  dim3(128), 0, stream>>>(num, mbuf, lbuf, attnb);
  k_gemm_o  <<<dim3(32,4),     dim3(256), 0, stream>>>(attnb, ow, outp);
}